// Round 12
// baseline (4512.679 us; speedup 1.0000x reference)
//
#include <hip/hip_runtime.h>

// out = Z + ((P@Z)@M @ (Z^T @ (Q@Z))) / N ; M[r,c]=0.9^(r-c) lower-tri (r,c<4096)
// Interior (rows/cols 0..4095) = 16x16 tiles of 256 per GEMM -> grids of exactly
// 256/512 blocks (1 block/CU, whole rounds). Overhang row/col 4096 via
// wave-per-dot border kernels. QZt computed directly as Zt @ Q^T (no transpose).
// GEMM4 K = 4096 exactly.
// Round-12 GEMM: register-pipelined 2-interval schedule. Every MFMA cluster's
// operands were read ONE INTERVAL EARLIER (zero lgkm wait at cluster start ->
// MFMA hides under other waves' LDS reads). Fragment regs reused via WAR
// (MFMA issued before the overwriting ds_read). Counted vmcnt(4) per interval
// drains exactly the half-tile staged one interval ago (ledger verified);
// lgkmcnt(0)+barrier+sched_barrier(0) at interval end (rule-18 fence).
// Chain: b0=Pb, b3=Qb, b1=Zt
//   dual:  PZ(int) = Pb@Z -> b2 ; QZt(int) = Zt@Q^T -> dox
//   border1: PZ row4096 ; QZt row4096 + cols4096..4159
//   left = decay_scan(PZ) -> b0   (rows 0..4096, cols 0..4095)
//   gemm3: rightT(int) = QZt@Zt^T -> b2 ; border2: rightT row4096
//   gemm4: out(int) = Z + left@rightT^T /4096 -> d_out (f32)
//   border3: out row4096 + col4096

typedef __attribute__((ext_vector_type(8))) short short8;
typedef __attribute__((ext_vector_type(4))) float f32x4;
typedef __attribute__((ext_vector_type(4))) unsigned short u16x4;

#define NPAD 4352   // row stride, 17*256
#define NV   4097
#define NCTX 4096
#define NT   65     // K-tiles for GEMM1-3 (4160 >= 4097)
#define NT4  64     // K-tiles for GEMM4 (4096 exact)

__device__ __forceinline__ float b2f(unsigned short u) {
  return __uint_as_float(((unsigned)u) << 16);
}
__device__ __forceinline__ unsigned short f2b(float f) {
  unsigned b = __float_as_uint(f);
  return (unsigned short)((b + 0x7FFFu + ((b >> 16) & 1u)) >> 16);
}
__device__ __forceinline__ void gload16(const void* g, void* l) {
  __builtin_amdgcn_global_load_lds(
      (const __attribute__((address_space(1))) unsigned int*)g,
      (__attribute__((address_space(3))) unsigned int*)l, 16, 0, 0);
}
__device__ __forceinline__ float wave_sum(float v) {
#pragma unroll
  for (int m = 1; m < 64; m <<= 1) v += __shfl_xor(v, m);
  return v;
}

// -------- fused cast + zero-pad: f32 [4097x4097] -> bf16 [4352x4352], P and Q -
__global__ __launch_bounds__(256) void cast_pad2(const float* __restrict__ inP,
                                                 unsigned short* __restrict__ outP,
                                                 const float* __restrict__ inQ,
                                                 unsigned short* __restrict__ outQ) {
  int bid = blockIdx.x;
  const float* in = inP;
  unsigned short* out = outP;
  if (bid >= 18496) { bid -= 18496; in = inQ; out = outQ; }
  int idx = bid * 256 + threadIdx.x;  // 4352 * 1088 quads
  int r = idx / 1088;
  int c4 = (idx - r * 1088) * 4;
  u16x4 o = {0, 0, 0, 0};
  if (r < NV) {
    const float* p = in + (size_t)r * NV + c4;
#pragma unroll
    for (int j = 0; j < 4; ++j) {
      float v = (c4 + j < NV) ? p[j] : 0.f;
      o[j] = f2b(v);
    }
  }
  *(u16x4*)&out[(size_t)r * NPAD + c4] = o;
}

// ------------- transpose-cast: f32 [4097x4097] -> bf16^T [4352x4352] ----------
__global__ __launch_bounds__(256) void transpose_cast(const float* __restrict__ in,
                                                      unsigned short* __restrict__ out) {
  __shared__ float tile[32][33];
  int x = threadIdx.x & 31;
  int y = threadIdx.x >> 5;
  int bx = blockIdx.x, by = blockIdx.y;
  int ic = bx * 32 + x;
#pragma unroll
  for (int j = 0; j < 4; ++j) {
    int ir = by * 32 + y + j * 8;
    float v = (ir < NV && ic < NV) ? in[(size_t)ir * NV + ic] : 0.f;
    tile[y + j * 8][x] = v;
  }
  __syncthreads();
  int orow = bx * 32;
  int ocol = by * 32 + x;
#pragma unroll
  for (int j = 0; j < 4; ++j) {
    out[(size_t)(orow + y + j * 8) * NPAD + ocol] = f2b(tile[x][y + j * 8]);
  }
}

// ------------- decay scan v2: 4 output chunks per wave ------------------------
__global__ __launch_bounds__(256) void decay_scan(const unsigned short* __restrict__ PZ,
                                                  unsigned short* __restrict__ L) {
  const int wid = (blockIdx.x << 2) | ((int)threadIdx.x >> 6);
  if (wid >= NV * 16) return;
  const int lane = threadIdx.x & 63;
  const int row = wid >> 4;
  const int g = wid & 15;
  const int c0 = g * 256;

  const float l2l = -0.15200309344504995f;  // log2(0.9)
  const float pl = exp2f((float)lane * l2l);           // 0.9^lane
  const float plc = exp2f((float)(64 - lane) * l2l);   // 0.9^(64-lane)

  const unsigned short* prow = PZ + (size_t)row * NPAD;
  float x[8];
#pragma unroll
  for (int d = 0; d < 8; ++d) {
    int c = c0 + d * 64 + lane;
    x[d] = (c < NCTX) ? b2f(prow[c]) : 0.f;
  }
  float S[8];
#pragma unroll
  for (int d = 1; d < 8; ++d) {
    float v = x[d] * pl;
#pragma unroll
    for (int i = 0; i < 6; ++i) v += __shfl_xor(v, 1 << i);
    S[d] = v;
  }
  const float pw[6] = {0.9f, 0.81f, 0.6561f, 0.43046721f,
                       0.18530201888518410f, 0.03433683820292512f};
  const float cw1 = 1.1790184577738583e-3f;   // 0.9^64
  const float cw2 = 1.3900845237714557e-6f;   // 0.9^128
  const float cw3 = 1.6389541800e-9f;         // 0.9^192
#pragma unroll
  for (int j = 0; j < 4; ++j) {
    float s = x[j];
#pragma unroll
    for (int i = 0; i < 6; ++i) {
      int tt = 1 << i;
      float o = __shfl_down(s, tt);
      s += (lane + tt < 64) ? pw[i] * o : 0.f;
    }
    float carry = S[j + 1] + cw1 * S[j + 2] + cw2 * S[j + 3] + cw3 * S[j + 4];
    float left = s + plc * carry;
    L[(size_t)row * NPAD + c0 + j * 64 + lane] = f2b(left);
  }
}

// ------------- 256x256 register-pipelined bf16 GEMM (interior tiles) ----------
// MODE 0: dual batch, 512 blocks (2 exact rounds); bf16 out.
// MODE 1: single, 256 blocks (1 round); bf16 out.
// MODE 2: single, 256 blocks; K=64 tiles; f32 out = Zin + acc/4096 (no guards).
template <int MODE>
__global__ __launch_bounds__(512, 2) void gemm256(
    const unsigned short* __restrict__ A0, const unsigned short* __restrict__ Bt0,
    unsigned short* __restrict__ C0,
    const unsigned short* __restrict__ A1, const unsigned short* __restrict__ Bt1,
    unsigned short* __restrict__ C1,
    float* __restrict__ Cf, const float* __restrict__ Zin) {
  __shared__ __align__(16) unsigned short Asm[2][256 * 64];
  __shared__ __align__(16) unsigned short Bsm[2][256 * 64];

  const int tid = threadIdx.x;
  const int lane = tid & 63;
  const int w = tid >> 6;
  const int wr = w >> 2, wc = w & 3;
  const int q = lane >> 4, r16 = lane & 15;

  // XCD swizzle (NFULL % 8 == 0 -> simple form is bijective)
  const int NFULL = (MODE == 0) ? 512 : 256;
  const int cpx = NFULL >> 3;
  int orig = blockIdx.x;
  int wg = (orig & 7) * cpx + (orig >> 3);

  const unsigned short* Am;
  const unsigned short* Btm;
  unsigned short* Co;
  if (MODE == 0) {
    int batch = wg >> 8;
    Am = batch ? A1 : A0;
    Btm = batch ? Bt1 : Bt0;
    Co = batch ? C1 : C0;
    wg &= 255;
  } else {
    Am = A0; Btm = Bt0; Co = C0;
  }
  const int by = wg >> 4, bx = wg & 15;
  const int brow = by * 256, bcol = bx * 256;
  const int KE = (MODE == 2) ? NT4 : NT;

  // staging: linear LDS dest (global_load_lds), inverse-swizzled global source.
  auto stageA = [&](int ktile, int mq, int bb) {
#pragma unroll
    for (int it = 0; it < 2; ++it) {
      int sub = w * 16 + it * 8;
      int row0 = mq * 64 + sub + (sub & 64);
      int row = row0 + (lane >> 3);
      int win = (lane & 7) ^ (row & 7);
      gload16(Am + (size_t)(brow + row) * NPAD + ktile * 64 + win * 8,
              &Asm[bb][row0 * 64]);
    }
  };
  auto stageB = [&](int ktile, int nq, int bb) {
#pragma unroll
    for (int it = 0; it < 2; ++it) {
      int sub = w * 16 + it * 8;
      int row0 = ((sub >> 5) << 6) + nq * 32 + (sub & 31);
      int row = row0 + (lane >> 3);
      int win = (lane & 7) ^ (row & 7);
      gload16(Btm + (size_t)(bcol + row) * NPAD + ktile * 64 + win * 8,
              &Bsm[bb][row0 * 64]);
    }
  };

  short8 a[4][2], b0r[2][2], b1r[2][2];
  auto rdA = [&](int mq, int bb) {
#pragma unroll
    for (int m = 0; m < 4; ++m) {
      int row = wr * 128 + mq * 64 + m * 16 + r16;
#pragma unroll
      for (int kk = 0; kk < 2; ++kk) {
        int win = (q + kk * 4) ^ (r16 & 7);
        a[m][kk] = *(const short8*)&Asm[bb][row * 64 + win * 8];
      }
    }
  };
  auto rdB = [&](short8 (&b)[2][2], int nq, int bb) {
#pragma unroll
    for (int n = 0; n < 2; ++n) {
      int row = wc * 64 + nq * 32 + n * 16 + r16;
#pragma unroll
      for (int kk = 0; kk < 2; ++kk) {
        int win = (q + kk * 4) ^ (r16 & 7);
        b[n][kk] = *(const short8*)&Bsm[bb][row * 64 + win * 8];
      }
    }
  };

  f32x4 acc[8][4] = {};

  // 32-MFMA cluster: one mq half (4 m-frags) x both nq quadrants x K=64.
  auto mma2 = [&](int mq) {
    __builtin_amdgcn_s_setprio(1);
#pragma unroll
    for (int kk = 0; kk < 2; ++kk)
#pragma unroll
      for (int m = 0; m < 4; ++m) {
#pragma unroll
        for (int n = 0; n < 2; ++n)
          acc[mq * 4 + m][n] = __builtin_amdgcn_mfma_f32_16x16x32_bf16(
              a[m][kk], b0r[n][kk], acc[mq * 4 + m][n], 0, 0, 0);
#pragma unroll
        for (int n = 0; n < 2; ++n)
          acc[mq * 4 + m][2 + n] = __builtin_amdgcn_mfma_f32_16x16x32_bf16(
              a[m][kk], b1r[n][kk], acc[mq * 4 + m][2 + n], 0, 0, 0);
      }
    __builtin_amdgcn_s_setprio(0);
  };

  // prologue: tile0 fully -> buf0 ; drain ; barrier.
  stageA(0, 0, 0); stageB(0, 0, 0); stageA(0, 1, 0); stageB(0, 1, 0);
  asm volatile("s_waitcnt vmcnt(0)" ::: "memory");
  __builtin_amdgcn_s_barrier();
  __builtin_amdgcn_sched_barrier(0);
  // I_even(0): read B(0), A0(0) from buf0 ; stage A0B0(1) -> buf1.
  rdB(b0r, 0, 0);
  rdB(b1r, 1, 0);
  rdA(0, 0);
  if (1 < KE) { stageA(1, 0, 1); stageB(1, 0, 1); }
  asm volatile("s_waitcnt lgkmcnt(0)" ::: "memory");
  __builtin_amdgcn_s_barrier();
  __builtin_amdgcn_sched_barrier(0);

  for (int kt = 0; kt < KE; ++kt) {
    const int bb = kt & 1;
    // I_odd(kt): M1(kt) = mma2(0) [operands read last interval, zero wait];
    // read A1(kt) into a (WAR: after MFMA issue); stage A1B1(kt+1) -> bb^1;
    // vmcnt(4) drains A0B0(kt+1) staged one interval ago.
    mma2(0);
    rdA(1, bb);
    if (kt + 1 < KE) { stageA(kt + 1, 1, bb ^ 1); stageB(kt + 1, 1, bb ^ 1); }
    if (kt + 1 < KE) { asm volatile("s_waitcnt vmcnt(4)" ::: "memory"); }
    else             { asm volatile("s_waitcnt vmcnt(0)" ::: "memory"); }
    asm volatile("s_waitcnt lgkmcnt(0)" ::: "memory");
    __builtin_amdgcn_s_barrier();
    __builtin_amdgcn_sched_barrier(0);
    if (kt + 1 == KE) break;  // final M2 below
    // I_even(kt+1): M2(kt) = mma2(1) [uses A1(kt), B(kt) regs; zero wait];
    // read B(kt+1), A0(kt+1) from bb^1 (WAR after MFMA); stage A0B0(kt+2) -> bb;
    // vmcnt(4) drains A1B1(kt+1) staged one interval ago.
    mma2(1);
    rdB(b0r, 0, bb ^ 1);
    rdB(b1r, 1, bb ^ 1);
    rdA(0, bb ^ 1);
    if (kt + 2 < KE) { stageA(kt + 2, 0, bb); stageB(kt + 2, 0, bb); }
    if (kt + 2 < KE) { asm volatile("s_waitcnt vmcnt(4)" ::: "memory"); }
    else             { asm volatile("s_waitcnt vmcnt(0)" ::: "memory"); }
    asm volatile("s_waitcnt lgkmcnt(0)" ::: "memory");
    __builtin_amdgcn_s_barrier();
    __builtin_amdgcn_sched_barrier(0);
  }
  mma2(1);  // M2(KE-1)

#pragma unroll
  for (int m = 0; m < 8; ++m) {
    const int row = brow + wr * 128 + m * 16 + q * 4;
#pragma unroll
    for (int n = 0; n < 4; ++n) {
      const int col = bcol + wc * 64 + n * 16 + r16;
#pragma unroll
      for (int v = 0; v < 4; ++v) {
        float val = acc[m][n][v];
        if (MODE == 2) {
          size_t o = (size_t)(row + v) * NV + col;   // row,col <= 4095 always
          Cf[o] = Zin[o] + val * (1.0f / 4096.0f);
        } else {
          Co[(size_t)(row + v) * NPAD + col] = f2b(val);
        }
      }
    }
  }
}

// ------------- border1 (wave-per-dot): overhang row/col for PZ and QZt --------
__global__ __launch_bounds__(256) void border1(
    const unsigned short* __restrict__ Pb, const unsigned short* __restrict__ Qb,
    const unsigned short* __restrict__ Zt,
    unsigned short* __restrict__ PZ, unsigned short* __restrict__ QZt) {
  const int wid = blockIdx.x * 4 + ((int)threadIdx.x >> 6);
  const int lane = threadIdx.x & 63;
  if (wid < 4096) {
    const int t = wid;
    const unsigned short* z = Zt + (size_t)t * NPAD;
    const unsigned short* p = Pb + (size_t)4096 * NPAD;
    const unsigned short* qq = Qb + (size_t)4096 * NPAD;
    float ap = 0.f, aq = 0.f;
    for (int k = lane * 8; k < 4104; k += 512) {
      short8 zv = *(const short8*)&z[k];
      short8 pv = *(const short8*)&p[k];
      short8 qv = *(const short8*)&qq[k];
#pragma unroll
      for (int j = 0; j < 8; ++j) {
        float zf = b2f((unsigned short)zv[j]);
        ap += zf * b2f((unsigned short)pv[j]);
        aq += zf * b2f((unsigned short)qv[j]);
      }
    }
    ap = wave_sum(ap);
    aq = wave_sum(aq);
    if (lane == 0) PZ[(size_t)4096 * NPAD + t] = f2b(ap);
    QZt[(size_t)t * NPAD + 4096 + lane] = (lane == 0) ? f2b(aq) : (unsigned short)0;
  } else {
    const int j = wid - 4096;
    if (j >= 4160) return;
    const unsigned short* qr = Qb + (size_t)j * NPAD;
    const unsigned short* zr = Zt + (size_t)4096 * NPAD;
    float a = 0.f;
    for (int k = lane * 8; k < 4104; k += 512) {
      short8 qv = *(const short8*)&qr[k];
      short8 zv = *(const short8*)&zr[k];
#pragma unroll
      for (int jj = 0; jj < 8; ++jj)
        a += b2f((unsigned short)qv[jj]) * b2f((unsigned short)zv[jj]);
    }
    a = wave_sum(a);
    if (lane == 0) QZt[(size_t)4096 * NPAD + j] = f2b(a);
  }
}

// ------------- border2 (wave-per-dot): rightT[4096][t] = QZt[4096,:].Zt[t,:] --
__global__ __launch_bounds__(256) void border2(const unsigned short* __restrict__ QZt,
                                               const unsigned short* __restrict__ Zt,
                                               unsigned short* __restrict__ RT) {
  const int t = blockIdx.x * 4 + ((int)threadIdx.x >> 6);
  const int lane = threadIdx.x & 63;
  const unsigned short* a = QZt + (size_t)4096 * NPAD;
  const unsigned short* z = Zt + (size_t)t * NPAD;
  float s = 0.f;
  for (int k = lane * 8; k < 4104; k += 512) {
    short8 av = *(const short8*)&a[k];
    short8 zv = *(const short8*)&z[k];
#pragma unroll
    for (int j = 0; j < 8; ++j)
      s += b2f((unsigned short)av[j]) * b2f((unsigned short)zv[j]);
  }
  s = wave_sum(s);
  if (lane == 0) RT[(size_t)4096 * NPAD + t] = f2b(s);
}

// ------------- border3 (wave-per-dot): out row 4096 + col 4096 ----------------
__global__ __launch_bounds__(256) void border3(const unsigned short* __restrict__ L,
                                               const unsigned short* __restrict__ RT,
                                               const float* __restrict__ Z,
                                               float* __restrict__ out) {
  const int wid = blockIdx.x * 4 + ((int)threadIdx.x >> 6);
  const int lane = threadIdx.x & 63;
  const unsigned short *lr, *rr;
  size_t o;
  if (wid < 4097) {
    lr = L + (size_t)4096 * NPAD;
    rr = RT + (size_t)wid * NPAD;
    o = (size_t)4096 * NV + wid;
  } else {
    const int r = wid - 4097;
    if (r >= 4096) return;
    lr = L + (size_t)r * NPAD;
    rr = RT + (size_t)4096 * NPAD;
    o = (size_t)r * NV + 4096;
  }
  float s = 0.f;
#pragma unroll 2
  for (int i = 0; i < 8; ++i) {
    int k = lane * 8 + i * 512;
    short8 lv = *(const short8*)&lr[k];
    short8 rv = *(const short8*)&rr[k];
#pragma unroll
    for (int j = 0; j < 8; ++j)
      s += b2f((unsigned short)lv[j]) * b2f((unsigned short)rv[j]);
  }
  s = wave_sum(s);
  if (lane == 0) out[o] = Z[o] + s * (1.0f / 4096.0f);
}

extern "C" void kernel_launch(void* const* d_in, const int* in_sizes, int n_in,
                              void* d_out, int out_size, void* d_ws, size_t ws_size,
                              hipStream_t stream) {
  (void)in_sizes; (void)n_in; (void)out_size; (void)ws_size;
  const float* Z = (const float*)d_in[0];
  const float* P = (const float*)d_in[1];
  const float* Q = (const float*)d_in[2];
  float* out = (float*)d_out;

  const size_t SZ = (size_t)NPAD * NPAD;
  unsigned short* b0 = (unsigned short*)d_ws;     // Pb -> left
  unsigned short* b1 = b0 + SZ;                   // Zt
  unsigned short* b2 = b1 + SZ;                   // PZ -> rightT
  unsigned short* b3 = b2 + SZ;                   // Qb
  unsigned short* dox = (unsigned short*)d_out;   // QZt (bf16, dead before f32 out)

  dim3 blk(256), blk5(512);
  dim3 gt(136, 136);

  cast_pad2<<<36992, blk, 0, stream>>>(P, b0, Q, b3);         // b0=Pb, b3=Qb
  transpose_cast<<<gt, blk, 0, stream>>>(Z, b1);              // b1 = Zt
  // dual: PZ = Pb@Z -> b2 ; QZt = Zt@Q^T -> dox (interior tiles)
  gemm256<0><<<512, blk5, 0, stream>>>(b0, b1, b2, b1, b3, dox, nullptr, nullptr);
  border1<<<2064, blk, 0, stream>>>(b0, b3, b1, b2, dox);     // overhang row/col
  decay_scan<<<16388, blk, 0, stream>>>(b2, b0);              // left (rows 0..4096)
  // rightT = QZt @ Zt^T -> b2 (interior)
  gemm256<1><<<256, blk5, 0, stream>>>(dox, b1, b2, nullptr, nullptr, nullptr,
                                       nullptr, nullptr);
  border2<<<1024, blk, 0, stream>>>(dox, b1, b2);             // rightT row 4096
  // out = Z + left @ rightT^T / 4096 (interior, f32)
  gemm256<2><<<256, blk5, 0, stream>>>(b0, b2, nullptr, nullptr, nullptr, nullptr,
                                       out, Z);
  border3<<<2049, blk, 0, stream>>>(b0, b2, Z, out);          // out row/col 4096
}

// Round 13
// 605.569 us; speedup vs baseline: 7.4520x; 7.4520x over previous
//
#include <hip/hip_runtime.h>

// out = Z + ((P@Z)@M @ (Z^T @ (Q@Z))) / N ; M[r,c]=0.9^(r-c) lower-tri (r,c<4096)
// Interior (rows/cols 0..4095) = 16x16 tiles of 256 per GEMM -> grids of exactly
// 256/512 blocks (1 block/CU, whole rounds). Overhang row/col 4096 via
// wave-per-dot border kernels. QZt computed directly as Zt @ Q^T (no transpose).
// GEMM4 K = 4096 exactly.
// GEMM schedule (round-10 fixed point, reverted after r11/r12 regressions):
// 2 barriers/K-tile + COUNTED vmcnt(4). Ledger: I2's vmcnt(4) sees
// {kt+1 A0B0, kt+1 A1B1, kt+2 A0B0} = 12 -> drains 8 oldest = tile kt+1
// complete before bar-B. Tail (kt>=KE-2): vmcnt(0). Stage-vs-read: stages into
// bb touch mq0/nq0 regions, read only in I1 and lgkm-drained before bar-A
// (mma2(0) consumes them); rdA(1) rows disjoint.
// [r11 lesson: per-tile vmcnt(0) stalls on just-issued loads (T4).]
// [r12 lesson: sched_barrier(0) fences + cross-interval reg pipeline -> the
//  allocator spills acc to scratch (WRITE 65MB->4.9GB) -> 10x regression.]
// Chain: b0=Pb, b3=Qb, b1=Zt
//   dual:  PZ(int) = Pb@Z -> b2 ; QZt(int) = Zt@Q^T -> dox
//   border1: PZ row4096 ; QZt row4096 + cols4096..4159
//   left = decay_scan(PZ) -> b0   (rows 0..4096, cols 0..4095)
//   gemm3: rightT(int) = QZt@Zt^T -> b2 ; border2: rightT row4096
//   gemm4: out(int) = Z + left@rightT^T /4096 -> d_out (f32)
//   border3: out row4096 + col4096

typedef __attribute__((ext_vector_type(8))) short short8;
typedef __attribute__((ext_vector_type(4))) float f32x4;
typedef __attribute__((ext_vector_type(4))) unsigned short u16x4;

#define NPAD 4352   // row stride, 17*256
#define NV   4097
#define NCTX 4096
#define NT   65     // K-tiles for GEMM1-3 (4160 >= 4097)
#define NT4  64     // K-tiles for GEMM4 (4096 exact)

__device__ __forceinline__ float b2f(unsigned short u) {
  return __uint_as_float(((unsigned)u) << 16);
}
__device__ __forceinline__ unsigned short f2b(float f) {
  unsigned b = __float_as_uint(f);
  return (unsigned short)((b + 0x7FFFu + ((b >> 16) & 1u)) >> 16);
}
__device__ __forceinline__ void gload16(const void* g, void* l) {
  __builtin_amdgcn_global_load_lds(
      (const __attribute__((address_space(1))) unsigned int*)g,
      (__attribute__((address_space(3))) unsigned int*)l, 16, 0, 0);
}
__device__ __forceinline__ float wave_sum(float v) {
#pragma unroll
  for (int m = 1; m < 64; m <<= 1) v += __shfl_xor(v, m);
  return v;
}

// -------- fused cast + zero-pad: f32 [4097x4097] -> bf16 [4352x4352], P and Q -
__global__ __launch_bounds__(256) void cast_pad2(const float* __restrict__ inP,
                                                 unsigned short* __restrict__ outP,
                                                 const float* __restrict__ inQ,
                                                 unsigned short* __restrict__ outQ) {
  int bid = blockIdx.x;
  const float* in = inP;
  unsigned short* out = outP;
  if (bid >= 18496) { bid -= 18496; in = inQ; out = outQ; }
  int idx = bid * 256 + threadIdx.x;  // 4352 * 1088 quads
  int r = idx / 1088;
  int c4 = (idx - r * 1088) * 4;
  u16x4 o = {0, 0, 0, 0};
  if (r < NV) {
    const float* p = in + (size_t)r * NV + c4;
#pragma unroll
    for (int j = 0; j < 4; ++j) {
      float v = (c4 + j < NV) ? p[j] : 0.f;
      o[j] = f2b(v);
    }
  }
  *(u16x4*)&out[(size_t)r * NPAD + c4] = o;
}

// ------------- transpose-cast: f32 [4097x4097] -> bf16^T [4352x4352] ----------
__global__ __launch_bounds__(256) void transpose_cast(const float* __restrict__ in,
                                                      unsigned short* __restrict__ out) {
  __shared__ float tile[32][33];
  int x = threadIdx.x & 31;
  int y = threadIdx.x >> 5;
  int bx = blockIdx.x, by = blockIdx.y;
  int ic = bx * 32 + x;
#pragma unroll
  for (int j = 0; j < 4; ++j) {
    int ir = by * 32 + y + j * 8;
    float v = (ir < NV && ic < NV) ? in[(size_t)ir * NV + ic] : 0.f;
    tile[y + j * 8][x] = v;
  }
  __syncthreads();
  int orow = bx * 32;
  int ocol = by * 32 + x;
#pragma unroll
  for (int j = 0; j < 4; ++j) {
    out[(size_t)(orow + y + j * 8) * NPAD + ocol] = f2b(tile[x][y + j * 8]);
  }
}

// ------------- decay scan v2: 4 output chunks per wave ------------------------
__global__ __launch_bounds__(256) void decay_scan(const unsigned short* __restrict__ PZ,
                                                  unsigned short* __restrict__ L) {
  const int wid = (blockIdx.x << 2) | ((int)threadIdx.x >> 6);
  if (wid >= NV * 16) return;
  const int lane = threadIdx.x & 63;
  const int row = wid >> 4;
  const int g = wid & 15;
  const int c0 = g * 256;

  const float l2l = -0.15200309344504995f;  // log2(0.9)
  const float pl = exp2f((float)lane * l2l);           // 0.9^lane
  const float plc = exp2f((float)(64 - lane) * l2l);   // 0.9^(64-lane)

  const unsigned short* prow = PZ + (size_t)row * NPAD;
  float x[8];
#pragma unroll
  for (int d = 0; d < 8; ++d) {
    int c = c0 + d * 64 + lane;
    x[d] = (c < NCTX) ? b2f(prow[c]) : 0.f;
  }
  float S[8];
#pragma unroll
  for (int d = 1; d < 8; ++d) {
    float v = x[d] * pl;
#pragma unroll
    for (int i = 0; i < 6; ++i) v += __shfl_xor(v, 1 << i);
    S[d] = v;
  }
  const float pw[6] = {0.9f, 0.81f, 0.6561f, 0.43046721f,
                       0.18530201888518410f, 0.03433683820292512f};
  const float cw1 = 1.1790184577738583e-3f;   // 0.9^64
  const float cw2 = 1.3900845237714557e-6f;   // 0.9^128
  const float cw3 = 1.6389541800e-9f;         // 0.9^192
#pragma unroll
  for (int j = 0; j < 4; ++j) {
    float s = x[j];
#pragma unroll
    for (int i = 0; i < 6; ++i) {
      int tt = 1 << i;
      float o = __shfl_down(s, tt);
      s += (lane + tt < 64) ? pw[i] * o : 0.f;
    }
    float carry = S[j + 1] + cw1 * S[j + 2] + cw2 * S[j + 3] + cw3 * S[j + 4];
    float left = s + plc * carry;
    L[(size_t)row * NPAD + c0 + j * 64 + lane] = f2b(left);
  }
}

// ------------- 256x256 2-barrier counted-vmcnt bf16 GEMM ----------------------
// MODE 0: dual batch, 512 blocks (2 exact rounds); bf16 out.
// MODE 1: single, 256 blocks (1 round); bf16 out.
// MODE 2: single, 256 blocks; K=64 tiles; f32 out = Zin + acc/4096 (no guards).
template <int MODE>
__global__ __launch_bounds__(512, 2) void gemm256(
    const unsigned short* __restrict__ A0, const unsigned short* __restrict__ Bt0,
    unsigned short* __restrict__ C0,
    const unsigned short* __restrict__ A1, const unsigned short* __restrict__ Bt1,
    unsigned short* __restrict__ C1,
    float* __restrict__ Cf, const float* __restrict__ Zin) {
  __shared__ __align__(16) unsigned short Asm[2][256 * 64];
  __shared__ __align__(16) unsigned short Bsm[2][256 * 64];

  const int tid = threadIdx.x;
  const int lane = tid & 63;
  const int w = tid >> 6;
  const int wr = w >> 2, wc = w & 3;
  const int q = lane >> 4, r16 = lane & 15;

  // XCD swizzle (NFULL % 8 == 0 -> simple form is bijective)
  const int NFULL = (MODE == 0) ? 512 : 256;
  const int cpx = NFULL >> 3;
  int orig = blockIdx.x;
  int wg = (orig & 7) * cpx + (orig >> 3);

  const unsigned short* Am;
  const unsigned short* Btm;
  unsigned short* Co;
  if (MODE == 0) {
    int batch = wg >> 8;
    Am = batch ? A1 : A0;
    Btm = batch ? Bt1 : Bt0;
    Co = batch ? C1 : C0;
    wg &= 255;
  } else {
    Am = A0; Btm = Bt0; Co = C0;
  }
  const int by = wg >> 4, bx = wg & 15;
  const int brow = by * 256, bcol = bx * 256;
  const int KE = (MODE == 2) ? NT4 : NT;

  // staging: linear LDS dest (global_load_lds), inverse-swizzled global source.
  auto stageA = [&](int ktile, int mq, int bb) {
#pragma unroll
    for (int it = 0; it < 2; ++it) {
      int sub = w * 16 + it * 8;
      int row0 = mq * 64 + sub + (sub & 64);
      int row = row0 + (lane >> 3);
      int win = (lane & 7) ^ (row & 7);
      gload16(Am + (size_t)(brow + row) * NPAD + ktile * 64 + win * 8,
              &Asm[bb][row0 * 64]);
    }
  };
  auto stageB = [&](int ktile, int nq, int bb) {
#pragma unroll
    for (int it = 0; it < 2; ++it) {
      int sub = w * 16 + it * 8;
      int row0 = ((sub >> 5) << 6) + nq * 32 + (sub & 31);
      int row = row0 + (lane >> 3);
      int win = (lane & 7) ^ (row & 7);
      gload16(Btm + (size_t)(bcol + row) * NPAD + ktile * 64 + win * 8,
              &Bsm[bb][row0 * 64]);
    }
  };

  short8 a[4][2], b0r[2][2], b1r[2][2];
  auto rdA = [&](int mq, int bb) {
#pragma unroll
    for (int m = 0; m < 4; ++m) {
      int row = wr * 128 + mq * 64 + m * 16 + r16;
#pragma unroll
      for (int kk = 0; kk < 2; ++kk) {
        int win = (q + kk * 4) ^ (r16 & 7);
        a[m][kk] = *(const short8*)&Asm[bb][row * 64 + win * 8];
      }
    }
  };
  auto rdB = [&](short8 (&b)[2][2], int nq, int bb) {
#pragma unroll
    for (int n = 0; n < 2; ++n) {
      int row = wc * 64 + nq * 32 + n * 16 + r16;
#pragma unroll
      for (int kk = 0; kk < 2; ++kk) {
        int win = (q + kk * 4) ^ (r16 & 7);
        b[n][kk] = *(const short8*)&Bsm[bb][row * 64 + win * 8];
      }
    }
  };

  f32x4 acc[8][4] = {};

  // 32-MFMA cluster: one mq half (4 m-frags) x both nq quadrants x K=64.
  auto mma2 = [&](int mq) {
    __builtin_amdgcn_s_setprio(1);
#pragma unroll
    for (int kk = 0; kk < 2; ++kk)
#pragma unroll
      for (int m = 0; m < 4; ++m) {
#pragma unroll
        for (int n = 0; n < 2; ++n)
          acc[mq * 4 + m][n] = __builtin_amdgcn_mfma_f32_16x16x32_bf16(
              a[m][kk], b0r[n][kk], acc[mq * 4 + m][n], 0, 0, 0);
#pragma unroll
        for (int n = 0; n < 2; ++n)
          acc[mq * 4 + m][2 + n] = __builtin_amdgcn_mfma_f32_16x16x32_bf16(
              a[m][kk], b1r[n][kk], acc[mq * 4 + m][2 + n], 0, 0, 0);
      }
    __builtin_amdgcn_s_setprio(0);
  };

  // prologue: tile0 fully -> buf0 ; tile1 {A0,B0} -> buf1 ; drain tile0 (8 of 12).
  stageA(0, 0, 0); stageB(0, 0, 0); stageA(0, 1, 0); stageB(0, 1, 0);
  stageA(1, 0, 1); stageB(1, 0, 1);
  asm volatile("s_waitcnt vmcnt(4)" ::: "memory");
  __builtin_amdgcn_s_barrier();

  for (int kt = 0; kt < KE; ++kt) {
    const int bb = kt & 1;
    // I1: reads (A-mq0 + both B halves; consumed by mma2(0) -> lgkm-drained
    //     before bar-A) ; stage kt+1 {A1,B1} -> bb^1 ; MFMA
    rdA(0, bb);
    rdB(b0r, 0, bb);
    rdB(b1r, 1, bb);
    if (kt + 1 < KE) { stageA(kt + 1, 1, bb ^ 1); stageB(kt + 1, 1, bb ^ 1); }
    mma2(0);
    __builtin_amdgcn_s_barrier();
    // I2: read A-mq1 (disjoint from staged mq0 regions) ; stage kt+2 {A0,B0}
    //     -> bb ; COUNTED drain (8 oldest = tile kt+1) ; MFMA
    rdA(1, bb);
    if (kt + 2 < KE) { stageA(kt + 2, 0, bb); stageB(kt + 2, 0, bb); }
    if (kt < KE - 2) { asm volatile("s_waitcnt vmcnt(4)" ::: "memory"); }
    else             { asm volatile("s_waitcnt vmcnt(0)" ::: "memory"); }
    mma2(1);
    __builtin_amdgcn_s_barrier();
  }

#pragma unroll
  for (int m = 0; m < 8; ++m) {
    const int row = brow + wr * 128 + m * 16 + q * 4;
#pragma unroll
    for (int n = 0; n < 4; ++n) {
      const int col = bcol + wc * 64 + n * 16 + r16;
#pragma unroll
      for (int v = 0; v < 4; ++v) {
        float val = acc[m][n][v];
        if (MODE == 2) {
          size_t o = (size_t)(row + v) * NV + col;   // row,col <= 4095 always
          Cf[o] = Zin[o] + val * (1.0f / 4096.0f);
        } else {
          Co[(size_t)(row + v) * NPAD + col] = f2b(val);
        }
      }
    }
  }
}

// ------------- border1 (wave-per-dot): overhang row/col for PZ and QZt --------
__global__ __launch_bounds__(256) void border1(
    const unsigned short* __restrict__ Pb, const unsigned short* __restrict__ Qb,
    const unsigned short* __restrict__ Zt,
    unsigned short* __restrict__ PZ, unsigned short* __restrict__ QZt) {
  const int wid = blockIdx.x * 4 + ((int)threadIdx.x >> 6);
  const int lane = threadIdx.x & 63;
  if (wid < 4096) {
    const int t = wid;
    const unsigned short* z = Zt + (size_t)t * NPAD;
    const unsigned short* p = Pb + (size_t)4096 * NPAD;
    const unsigned short* qq = Qb + (size_t)4096 * NPAD;
    float ap = 0.f, aq = 0.f;
    for (int k = lane * 8; k < 4104; k += 512) {
      short8 zv = *(const short8*)&z[k];
      short8 pv = *(const short8*)&p[k];
      short8 qv = *(const short8*)&qq[k];
#pragma unroll
      for (int j = 0; j < 8; ++j) {
        float zf = b2f((unsigned short)zv[j]);
        ap += zf * b2f((unsigned short)pv[j]);
        aq += zf * b2f((unsigned short)qv[j]);
      }
    }
    ap = wave_sum(ap);
    aq = wave_sum(aq);
    if (lane == 0) PZ[(size_t)4096 * NPAD + t] = f2b(ap);
    QZt[(size_t)t * NPAD + 4096 + lane] = (lane == 0) ? f2b(aq) : (unsigned short)0;
  } else {
    const int j = wid - 4096;
    if (j >= 4160) return;
    const unsigned short* qr = Qb + (size_t)j * NPAD;
    const unsigned short* zr = Zt + (size_t)4096 * NPAD;
    float a = 0.f;
    for (int k = lane * 8; k < 4104; k += 512) {
      short8 qv = *(const short8*)&qr[k];
      short8 zv = *(const short8*)&zr[k];
#pragma unroll
      for (int jj = 0; jj < 8; ++jj)
        a += b2f((unsigned short)qv[jj]) * b2f((unsigned short)zv[jj]);
    }
    a = wave_sum(a);
    if (lane == 0) QZt[(size_t)4096 * NPAD + j] = f2b(a);
  }
}

// ------------- border2 (wave-per-dot): rightT[4096][t] = QZt[4096,:].Zt[t,:] --
__global__ __launch_bounds__(256) void border2(const unsigned short* __restrict__ QZt,
                                               const unsigned short* __restrict__ Zt,
                                               unsigned short* __restrict__ RT) {
  const int t = blockIdx.x * 4 + ((int)threadIdx.x >> 6);
  const int lane = threadIdx.x & 63;
  const unsigned short* a = QZt + (size_t)4096 * NPAD;
  const unsigned short* z = Zt + (size_t)t * NPAD;
  float s = 0.f;
  for (int k = lane * 8; k < 4104; k += 512) {
    short8 av = *(const short8*)&a[k];
    short8 zv = *(const short8*)&z[k];
#pragma unroll
    for (int j = 0; j < 8; ++j)
      s += b2f((unsigned short)av[j]) * b2f((unsigned short)zv[j]);
  }
  s = wave_sum(s);
  if (lane == 0) RT[(size_t)4096 * NPAD + t] = f2b(s);
}

// ------------- border3 (wave-per-dot): out row 4096 + col 4096 ----------------
__global__ __launch_bounds__(256) void border3(const unsigned short* __restrict__ L,
                                               const unsigned short* __restrict__ RT,
                                               const float* __restrict__ Z,
                                               float* __restrict__ out) {
  const int wid = blockIdx.x * 4 + ((int)threadIdx.x >> 6);
  const int lane = threadIdx.x & 63;
  const unsigned short *lr, *rr;
  size_t o;
  if (wid < 4097) {
    lr = L + (size_t)4096 * NPAD;
    rr = RT + (size_t)wid * NPAD;
    o = (size_t)4096 * NV + wid;
  } else {
    const int r = wid - 4097;
    if (r >= 4096) return;
    lr = L + (size_t)r * NPAD;
    rr = RT + (size_t)4096 * NPAD;
    o = (size_t)r * NV + 4096;
  }
  float s = 0.f;
#pragma unroll 2
  for (int i = 0; i < 8; ++i) {
    int k = lane * 8 + i * 512;
    short8 lv = *(const short8*)&lr[k];
    short8 rv = *(const short8*)&rr[k];
#pragma unroll
    for (int j = 0; j < 8; ++j)
      s += b2f((unsigned short)lv[j]) * b2f((unsigned short)rv[j]);
  }
  s = wave_sum(s);
  if (lane == 0) out[o] = Z[o] + s * (1.0f / 4096.0f);
}

extern "C" void kernel_launch(void* const* d_in, const int* in_sizes, int n_in,
                              void* d_out, int out_size, void* d_ws, size_t ws_size,
                              hipStream_t stream) {
  (void)in_sizes; (void)n_in; (void)out_size; (void)ws_size;
  const float* Z = (const float*)d_in[0];
  const float* P = (const float*)d_in[1];
  const float* Q = (const float*)d_in[2];
  float* out = (float*)d_out;

  const size_t SZ = (size_t)NPAD * NPAD;
  unsigned short* b0 = (unsigned short*)d_ws;     // Pb -> left
  unsigned short* b1 = b0 + SZ;                   // Zt
  unsigned short* b2 = b1 + SZ;                   // PZ -> rightT
  unsigned short* b3 = b2 + SZ;                   // Qb
  unsigned short* dox = (unsigned short*)d_out;   // QZt (bf16, dead before f32 out)

  dim3 blk(256), blk5(512);
  dim3 gt(136, 136);

  cast_pad2<<<36992, blk, 0, stream>>>(P, b0, Q, b3);         // b0=Pb, b3=Qb
  transpose_cast<<<gt, blk, 0, stream>>>(Z, b1);              // b1 = Zt
  // dual: PZ = Pb@Z -> b2 ; QZt = Zt@Q^T -> dox (interior tiles)
  gemm256<0><<<512, blk5, 0, stream>>>(b0, b1, b2, b1, b3, dox, nullptr, nullptr);
  border1<<<2064, blk, 0, stream>>>(b0, b3, b1, b2, dox);     // overhang row/col
  decay_scan<<<16388, blk, 0, stream>>>(b2, b0);              // left (rows 0..4096)
  // rightT = QZt @ Zt^T -> b2 (interior)
  gemm256<1><<<256, blk5, 0, stream>>>(dox, b1, b2, nullptr, nullptr, nullptr,
                                       nullptr, nullptr);
  border2<<<1024, blk, 0, stream>>>(dox, b1, b2);             // rightT row 4096
  // out = Z + left @ rightT^T / 4096 (interior, f32)
  gemm256<2><<<256, blk5, 0, stream>>>(b0, b2, nullptr, nullptr, nullptr, nullptr,
                                       out, Z);
  border3<<<2049, blk, 0, stream>>>(b0, b2, Z, out);          // out row/col 4096
}